// Round 4
// baseline (1167.741 us; speedup 1.0000x reference)
//
#include <hip/hip_runtime.h>
#include <hip/hip_fp16.h>
#include <math.h>

#define N_NODES 50000
#define N_EDGES 1600000
#define NBUCK 196          // dst >> 8
#define EBLK 200           // edge blocks for sort
#define CHUNK 8000         // edges per block (EBLK*CHUNK == N_EDGES)
#define NSLICE 4           // edge slices for deg histogram
#define SLICE_E 400000     // N_EDGES / NSLICE
#define NSUB 49            // node subranges of 1024 (49*1024 = 50176 >= 50000)

typedef _Float16 f16x8 __attribute__((ext_vector_type(8)));
typedef float f32x4 __attribute__((ext_vector_type(4)));

// ---------- bucket sort by dst (no device atomics) ----------
// Phase A: per-(edge-block, bucket) counts via LDS histogram
__global__ __launch_bounds__(256) void k_bcount(const int* __restrict__ dst,
                                                int* __restrict__ bcnt) {
    __shared__ int lc[256];
    int tid = threadIdx.x;
    lc[tid] = 0;
    __syncthreads();
    int base = blockIdx.x * CHUNK;
    for (int i = tid; i < CHUNK; i += 256)
        atomicAdd(&lc[dst[base + i] >> 8], 1);
    __syncthreads();
    bcnt[blockIdx.x * 256 + tid] = lc[tid];
}

// Phase B: bucket-major exclusive scan of bcnt[EBLK][256] (single block).
// Converts bcnt[k][b] into the global base offset for block k's bucket-b run.
__global__ __launch_bounds__(256) void k_bscan(int* __restrict__ bcnt,
                                               int* __restrict__ bucket_start,
                                               int* __restrict__ row_start) {
    int b = threadIdx.x;
    int run = 0;
    for (int k = 0; k < EBLK; k++) {
        int t = bcnt[k * 256 + b];
        bcnt[k * 256 + b] = run;
        run += t;
    }
    __shared__ int s[256];
    s[b] = run;
    __syncthreads();
    for (int off = 1; off < 256; off <<= 1) {
        int t = (b >= off) ? s[b - off] : 0;
        __syncthreads();
        s[b] += t;
        __syncthreads();
    }
    int bstart = s[b] - run;  // exclusive prefix
    bucket_start[b] = bstart;
    if (b == 0) {
        bucket_start[256] = N_EDGES;
        row_start[N_NODES] = N_EDGES;
    }
    for (int k = 0; k < EBLK; k++) bcnt[k * 256 + b] += bstart;
}

// Phase C: scatter edges into bucket-sorted order (LDS cursors, private ranges)
__global__ __launch_bounds__(256) void k_bscatter(const int* __restrict__ src,
                                                  const int* __restrict__ dst,
                                                  const float* __restrict__ w,
                                                  const int* __restrict__ bcnt,
                                                  int* __restrict__ edst,
                                                  uint2* __restrict__ esw) {
    __shared__ int cur[256];
    int tid = threadIdx.x;
    cur[tid] = bcnt[blockIdx.x * 256 + tid];
    __syncthreads();
    int base = blockIdx.x * CHUNK;
    for (int i = tid; i < CHUNK; i += 256) {
        int d = dst[base + i];
        int ss = src[base + i];
        float wi = w[base + i];
        int p = atomicAdd(&cur[d >> 8], 1);  // LDS atomic
        edst[p] = d;
        uint2 r; r.x = (unsigned)ss; r.y = __float_as_uint(wi);
        esw[p] = r;
    }
}

// ---------- deg[src] via replicated-read LDS histograms (no device atomics) ----------
// grid = NSLICE x NSUB; block (slice, sub) reads its edge slice coalesced and
// accumulates w for src in [sub*1024, sub*1024+1024) into LDS, then writes a
// private partial histogram.
__global__ __launch_bounds__(256) void k_deg_hist(const int* __restrict__ src,
                                                  const float* __restrict__ w,
                                                  float* __restrict__ degh) {
    __shared__ float h[1024];
    int tid = threadIdx.x;
    for (int i = tid; i < 1024; i += 256) h[i] = 0.f;
    __syncthreads();
    int slice = blockIdx.x / NSUB, sub = blockIdx.x % NSUB;
    int nbase = sub << 10;
    int e0 = slice * SLICE_E, e1 = e0 + SLICE_E;
    for (int i = e0 + tid; i < e1; i += 256) {
        int s = src[i];
        unsigned loc = (unsigned)(s - nbase);
        if (loc < 1024u) atomicAdd(&h[loc], w[i]);  // LDS atomic
    }
    __syncthreads();
    float* out = degh + ((size_t)blockIdx.x << 10);
    for (int i = tid; i < 1024; i += 256) out[i] = h[i];
}

// reduce the NSLICE partials and compute dinv in one pass
__global__ void k_dinv(const float* __restrict__ degh, float* __restrict__ dinv, int n) {
    int i = blockIdx.x * 256 + threadIdx.x;
    if (i < n) {
        int sub = i >> 10, off = i & 1023;
        float d = 0.f;
        for (int s = 0; s < NSLICE; s++)
            d += degh[(((size_t)(s * NSUB + sub)) << 10) + off];
        dinv[i] = d > 0.f ? rsqrtf(fmaxf(d, 1e-30f)) : 0.f;
    }
}

// Phase D: per-bucket CSR build + inline norm (one block per bucket)
__global__ __launch_bounds__(256) void k_bcsr(const int* __restrict__ edst,
                                              const uint2* __restrict__ esw,
                                              const int* __restrict__ bucket_start,
                                              const float* __restrict__ dinv,
                                              int* __restrict__ row_start,
                                              uint2* __restrict__ csr) {
    __shared__ int ncnt[256];
    __shared__ int cur[256];
    __shared__ int sc[256];
    __shared__ float ldinv[256];
    int tid = threadIdx.x;
    int b = blockIdx.x;
    int node = (b << 8) + tid;
    ncnt[tid] = 0;
    ldinv[tid] = (node < N_NODES) ? dinv[node] : 0.f;
    __syncthreads();
    int e0 = bucket_start[b], e1 = bucket_start[b + 1];
    for (int i = e0 + tid; i < e1; i += 256)
        atomicAdd(&ncnt[edst[i] & 255], 1);  // LDS atomic
    __syncthreads();
    int v = ncnt[tid];
    sc[tid] = v;
    __syncthreads();
    for (int off = 1; off < 256; off <<= 1) {
        int t = (tid >= off) ? sc[tid - off] : 0;
        __syncthreads();
        sc[tid] += t;
        __syncthreads();
    }
    int excl = sc[tid] - v;
    cur[tid] = excl;
    if (node < N_NODES) row_start[node] = e0 + excl;
    __syncthreads();
    for (int i = e0 + tid; i < e1; i += 256) {
        int d = edst[i];
        uint2 sw = esw[i];
        int ld = d & 255;
        int p = e0 + atomicAdd(&cur[ld], 1);  // LDS atomic
        float nv = -dinv[sw.x] * __uint_as_float(sw.y) * ldinv[ld];
        uint2 r; r.x = sw.x; r.y = __float_as_uint(nv);
        csr[p] = r;
    }
}

// copy x (50000x128 fp32) into Th slice 0 (f16, row stride 384)
__global__ void k_copy_x(const float* __restrict__ x, __half* __restrict__ Th, int n2) {
    int i = blockIdx.x * blockDim.x + threadIdx.x;  // half2 index
    if (i < n2) {
        int node = i >> 6;
        int c2 = (i & 63) * 2;
        float2 v = *(const float2*)&x[(size_t)node * 128 + c2];
        *(__half2*)&Th[(size_t)node * 384 + c2] = __floats2half2_rn(v.x, v.y);
    }
}

// W (384 x C fp32) -> Wt (C x 384 f16), Wt[n*384+k] = W[k*C+n]
__global__ void k_wt(const float* __restrict__ W, __half* __restrict__ Wt, int C) {
    int i = blockIdx.x * blockDim.x + threadIdx.x;
    if (i < C * 384) {
        int n = i / 384, k = i % 384;
        Wt[i] = __float2half(W[(size_t)k * C + n]);
    }
}

// ---------- SpMM: one wave per node, lane owns 2 f16 features ----------
// unrolled x8 (keeps 8 gathers in flight to cover L2/LLC latency)
__global__ __launch_bounds__(256) void k_spmm(__half* Th, const int* __restrict__ row_start,
                                              const uint2* __restrict__ csr,
                                              int in_off, int out_off, int mode) {
    int node = blockIdx.x * 4 + (threadIdx.x >> 6);
    int lane = threadIdx.x & 63;
    int s = row_start[node];
    int e = row_start[node + 1];
    const __half* Tin = Th + in_off + 2 * lane;
    float ax0 = 0.f, ay0 = 0.f, ax1 = 0.f, ay1 = 0.f;
    float ax2 = 0.f, ay2 = 0.f, ax3 = 0.f, ay3 = 0.f;
    float ax4 = 0.f, ay4 = 0.f, ax5 = 0.f, ay5 = 0.f;
    float ax6 = 0.f, ay6 = 0.f, ax7 = 0.f, ay7 = 0.f;
    int j = s;
    for (; j + 8 <= e; j += 8) {
        uint2 e0 = csr[j + 0], e1 = csr[j + 1], e2 = csr[j + 2], e3 = csr[j + 3];
        uint2 e4 = csr[j + 4], e5 = csr[j + 5], e6 = csr[j + 6], e7 = csr[j + 7];
        __half2 r0 = *(const __half2*)&Tin[(size_t)e0.x * 384];
        __half2 r1 = *(const __half2*)&Tin[(size_t)e1.x * 384];
        __half2 r2 = *(const __half2*)&Tin[(size_t)e2.x * 384];
        __half2 r3 = *(const __half2*)&Tin[(size_t)e3.x * 384];
        __half2 r4 = *(const __half2*)&Tin[(size_t)e4.x * 384];
        __half2 r5 = *(const __half2*)&Tin[(size_t)e5.x * 384];
        __half2 r6 = *(const __half2*)&Tin[(size_t)e6.x * 384];
        __half2 r7 = *(const __half2*)&Tin[(size_t)e7.x * 384];
        float2 f0 = __half22float2(r0), f1 = __half22float2(r1);
        float2 f2 = __half22float2(r2), f3 = __half22float2(r3);
        float2 f4 = __half22float2(r4), f5 = __half22float2(r5);
        float2 f6 = __half22float2(r6), f7 = __half22float2(r7);
        float n0 = __uint_as_float(e0.y), n1 = __uint_as_float(e1.y);
        float n2 = __uint_as_float(e2.y), n3 = __uint_as_float(e3.y);
        float n4 = __uint_as_float(e4.y), n5 = __uint_as_float(e5.y);
        float n6 = __uint_as_float(e6.y), n7 = __uint_as_float(e7.y);
        ax0 = fmaf(n0, f0.x, ax0); ay0 = fmaf(n0, f0.y, ay0);
        ax1 = fmaf(n1, f1.x, ax1); ay1 = fmaf(n1, f1.y, ay1);
        ax2 = fmaf(n2, f2.x, ax2); ay2 = fmaf(n2, f2.y, ay2);
        ax3 = fmaf(n3, f3.x, ax3); ay3 = fmaf(n3, f3.y, ay3);
        ax4 = fmaf(n4, f4.x, ax4); ay4 = fmaf(n4, f4.y, ay4);
        ax5 = fmaf(n5, f5.x, ax5); ay5 = fmaf(n5, f5.y, ay5);
        ax6 = fmaf(n6, f6.x, ax6); ay6 = fmaf(n6, f6.y, ay6);
        ax7 = fmaf(n7, f7.x, ax7); ay7 = fmaf(n7, f7.y, ay7);
    }
    for (; j < e; j++) {
        uint2 ee = csr[j];
        __half2 r = *(const __half2*)&Tin[(size_t)ee.x * 384];
        float2 f = __half22float2(r);
        float nv = __uint_as_float(ee.y);
        ax0 = fmaf(nv, f.x, ax0); ay0 = fmaf(nv, f.y, ay0);
    }
    float ax = ((ax0 + ax1) + (ax2 + ax3)) + ((ax4 + ax5) + (ax6 + ax7));
    float ay = ((ay0 + ay1) + (ay2 + ay3)) + ((ay4 + ay5) + (ay6 + ay7));
    float ox = ax, oy = ay;
    if (mode) {
        __half2 t0h = *(const __half2*)&Th[(size_t)node * 384 + 2 * lane];
        float2 t0 = __half22float2(t0h);
        ox = 2.f * ax - t0.x;
        oy = 2.f * ay - t0.y;
    }
    *(__half2*)&Th[(size_t)node * 384 + out_off + 2 * lane] = __floats2half2_rn(ox, oy);
}

// ---------- MFMA GEMM: out = sigmoid(A[Mx384 f16] @ Wt^T[384xC f16] + b) ----------
// mfma_f32_16x16x32_f16: A[m=lane&15][k=(lane>>4)*8+j]; C/D col=lane&15,row=(lane>>4)*4+r.
// A and out may alias (rows owned exclusively per block) -> no __restrict__.
template <int C>
__global__ __launch_bounds__(256) void k_gemm(const __half* A, const __half* __restrict__ Wt,
                                              const float* __restrict__ bias, void* out,
                                              int mode, int M) {
    constexpr int NF = C / 16;
    __shared__ _Float16 As[64][56];
    __shared__ _Float16 Bs[C][56];
    int tid = threadIdx.x;
    int wave = tid >> 6, lane = tid & 63;
    int lm = lane & 15, lq = lane >> 4;
    int m0 = blockIdx.x * 64;
    f32x4 acc[NF];
    for (int nf = 0; nf < NF; nf++) acc[nf] = (f32x4)0.0f;

    for (int k0 = 0; k0 < 384; k0 += 32) {
        {
            int r = tid >> 2, q = tid & 3;
            int row = m0 + r;
            if (row >= M) row = M - 1;
            *(f16x8*)&As[r][q * 8] = *(const f16x8*)&A[(size_t)row * 384 + k0 + q * 8];
        }
        for (int i = 0; i < (C * 4) / 256; i++) {
            int idx = tid + i * 256;
            int n = idx >> 2, q = idx & 3;
            *(f16x8*)&Bs[n][q * 8] = *(const f16x8*)&Wt[(size_t)n * 384 + k0 + q * 8];
        }
        __syncthreads();
        f16x8 a = *(const f16x8*)&As[wave * 16 + lm][lq * 8];
        for (int nf = 0; nf < NF; nf++) {
            f16x8 b = *(const f16x8*)&Bs[nf * 16 + lm][lq * 8];
            acc[nf] = __builtin_amdgcn_mfma_f32_16x16x32_f16(a, b, acc[nf], 0, 0, 0);
        }
        __syncthreads();
    }
    for (int nf = 0; nf < NF; nf++) {
        for (int r = 0; r < 4; r++) {
            int grow = m0 + wave * 16 + lq * 4 + r;
            int col = nf * 16 + lm;
            if (grow < M) {
                float v = acc[nf][r] + bias[col];
                v = 1.f / (1.f + expf(-v));
                if (mode == 0)
                    ((__half*)out)[(size_t)grow * 384 + col] = __float2half(v);
                else
                    ((float*)out)[(size_t)grow * C + col] = v;
            }
        }
    }
}

extern "C" void kernel_launch(void* const* d_in, const int* in_sizes, int n_in,
                              void* d_out, int out_size, void* d_ws, size_t ws_size,
                              hipStream_t stream) {
    const float* x  = (const float*)d_in[0];
    const int*   ei = (const int*)d_in[1];
    const float* ew = (const float*)d_in[2];
    const float* W0 = (const float*)d_in[3];
    const float* b0 = (const float*)d_in[4];
    const float* W1 = (const float*)d_in[5];
    const float* b1 = (const float*)d_in[6];
    const float* W2 = (const float*)d_in[7];
    const float* b2 = (const float*)d_in[8];
    const int* src = ei;
    const int* dst = ei + N_EDGES;

    char* ws = (char*)d_ws;
    size_t off = 0;
    auto alloc = [&](size_t bytes) -> char* {
        size_t p = (off + 255) & ~(size_t)255;
        off = p + bytes;
        return ws + p;
    };
    __half* Th        = (__half*)alloc((size_t)N_NODES * 384 * 2);     // [T0|T1|T2] f16
    uint2*  csr       = (uint2*)alloc((size_t)N_EDGES * 8);            // (src, norm)
    int*    edst      = (int*)alloc((size_t)N_EDGES * 4);              // bucket-sorted dst
    uint2*  esw       = (uint2*)alloc((size_t)N_EDGES * 8);            // bucket-sorted (src,w)
    int*    bcnt      = (int*)alloc((size_t)EBLK * 256 * 4);
    int*    bucket_start = (int*)alloc(257 * 4);
    int*    row_start = (int*)alloc((size_t)(N_NODES + 1) * 4);
    float*  degh      = (float*)alloc((size_t)NSLICE * NSUB * 1024 * 4);
    float*  dinv      = (float*)alloc((size_t)N_NODES * 4);
    __half* Wt0       = (__half*)alloc((size_t)128 * 384 * 2);
    __half* Wt1       = (__half*)alloc((size_t)128 * 384 * 2);
    __half* Wt2       = (__half*)alloc((size_t)64 * 384 * 2);

    // bucket sort by dst (no device atomics anywhere in preprocessing)
    k_bcount<<<EBLK, 256, 0, stream>>>(dst, bcnt);
    k_bscan<<<1, 256, 0, stream>>>(bcnt, bucket_start, row_start);
    k_bscatter<<<EBLK, 256, 0, stream>>>(src, dst, ew, bcnt, edst, esw);
    // deg/dinv via replicated-read LDS histograms
    k_deg_hist<<<NSLICE * NSUB, 256, 0, stream>>>(src, ew, degh);
    k_dinv<<<(N_NODES + 255) / 256, 256, 0, stream>>>(degh, dinv, N_NODES);
    // final CSR + inline norm
    k_bcsr<<<NBUCK, 256, 0, stream>>>(edst, esw, bucket_start, dinv, row_start, csr);

    k_copy_x<<<(N_NODES * 64 + 255) / 256, 256, 0, stream>>>(x, Th, N_NODES * 64);
    k_wt<<<(128 * 384 + 255) / 256, 256, 0, stream>>>(W0, Wt0, 128);
    k_wt<<<(128 * 384 + 255) / 256, 256, 0, stream>>>(W1, Wt1, 128);
    k_wt<<<(64 * 384 + 255) / 256, 256, 0, stream>>>(W2, Wt2, 64);

    const __half* Wl[3] = {Wt0, Wt1, Wt2};
    const float*  bl[3] = {b0, b1, b2};
    int gemm_blocks = (N_NODES + 63) / 64;
    for (int l = 0; l < 3; l++) {
        k_spmm<<<N_NODES / 4, 256, 0, stream>>>(Th, row_start, csr, 0, 128, 0);
        k_spmm<<<N_NODES / 4, 256, 0, stream>>>(Th, row_start, csr, 128, 256, 1);
        if (l < 2)
            k_gemm<128><<<gemm_blocks, 256, 0, stream>>>(Th, Wl[l], bl[l], Th, 0, N_NODES);
        else
            k_gemm<64><<<gemm_blocks, 256, 0, stream>>>(Th, Wl[l], bl[l], d_out, 1, N_NODES);
    }
}

// Round 5
// 664.233 us; speedup vs baseline: 1.7580x; 1.7580x over previous
//
#include <hip/hip_runtime.h>
#include <hip/hip_fp16.h>
#include <math.h>

#define N_NODES 50000
#define N_EDGES 1600000
#define NBUCK 196          // dst >> 8
#define EBLK 200           // edge blocks for sort
#define CHUNK 8000         // edges per block (EBLK*CHUNK == N_EDGES)

typedef _Float16 f16x8 __attribute__((ext_vector_type(8)));
typedef float f32x4 __attribute__((ext_vector_type(4)));

// ---------- bucket sort by dst ----------
// Phase A: per-(edge-block, bucket) counts via LDS histogram
__global__ __launch_bounds__(256) void k_bcount(const int* __restrict__ dst,
                                                int* __restrict__ bcnt) {
    __shared__ int lc[256];
    int tid = threadIdx.x;
    lc[tid] = 0;
    __syncthreads();
    int base = blockIdx.x * CHUNK;
    for (int i = tid; i < CHUNK; i += 256)
        atomicAdd(&lc[dst[base + i] >> 8], 1);
    __syncthreads();
    bcnt[blockIdx.x * 256 + tid] = lc[tid];
}

// Phase B: bucket-major exclusive scan of bcnt[EBLK][256] (single block).
__global__ __launch_bounds__(256) void k_bscan(int* __restrict__ bcnt,
                                               int* __restrict__ bucket_start,
                                               int* __restrict__ row_start) {
    int b = threadIdx.x;
    int run = 0;
    for (int k = 0; k < EBLK; k++) {
        int t = bcnt[k * 256 + b];
        bcnt[k * 256 + b] = run;
        run += t;
    }
    __shared__ int s[256];
    s[b] = run;
    __syncthreads();
    for (int off = 1; off < 256; off <<= 1) {
        int t = (b >= off) ? s[b - off] : 0;
        __syncthreads();
        s[b] += t;
        __syncthreads();
    }
    int bstart = s[b] - run;  // exclusive prefix
    bucket_start[b] = bstart;
    if (b == 0) {
        bucket_start[256] = N_EDGES;
        row_start[N_NODES] = N_EDGES;
    }
    for (int k = 0; k < EBLK; k++) bcnt[k * 256 + b] += bstart;
}

// Phase C: scatter edges into bucket-sorted order (LDS cursors, private ranges)
// + fused deg[src] device atomics (src/w already in registers here; the
// ~40us of scatter work overlaps the atomic drain).
__global__ __launch_bounds__(256) void k_bscatter(const int* __restrict__ src,
                                                  const int* __restrict__ dst,
                                                  const float* __restrict__ w,
                                                  const int* __restrict__ bcnt,
                                                  int* __restrict__ edst,
                                                  uint2* __restrict__ esw,
                                                  float* __restrict__ deg) {
    __shared__ int cur[256];
    int tid = threadIdx.x;
    cur[tid] = bcnt[blockIdx.x * 256 + tid];
    __syncthreads();
    int base = blockIdx.x * CHUNK;
    for (int i = tid; i < CHUNK; i += 256) {
        int d = dst[base + i];
        int ss = src[base + i];
        float wi = w[base + i];
        atomicAdd(&deg[ss], wi);
        int p = atomicAdd(&cur[d >> 8], 1);  // LDS atomic
        edst[p] = d;
        uint2 r; r.x = (unsigned)ss; r.y = __float_as_uint(wi);
        esw[p] = r;
    }
}

__global__ void k_dinv(float* deg, int n) {
    int i = blockIdx.x * 256 + threadIdx.x;
    if (i < n) {
        float d = deg[i];
        deg[i] = d > 0.f ? rsqrtf(fmaxf(d, 1e-30f)) : 0.f;
    }
}

// Phase D: per-bucket CSR build + inline norm (one block per bucket)
__global__ __launch_bounds__(256) void k_bcsr(const int* __restrict__ edst,
                                              const uint2* __restrict__ esw,
                                              const int* __restrict__ bucket_start,
                                              const float* __restrict__ dinv,
                                              int* __restrict__ row_start,
                                              uint2* __restrict__ csr) {
    __shared__ int ncnt[256];
    __shared__ int cur[256];
    __shared__ int sc[256];
    __shared__ float ldinv[256];
    int tid = threadIdx.x;
    int b = blockIdx.x;
    int node = (b << 8) + tid;
    ncnt[tid] = 0;
    ldinv[tid] = (node < N_NODES) ? dinv[node] : 0.f;
    __syncthreads();
    int e0 = bucket_start[b], e1 = bucket_start[b + 1];
    for (int i = e0 + tid; i < e1; i += 256)
        atomicAdd(&ncnt[edst[i] & 255], 1);  // LDS atomic
    __syncthreads();
    int v = ncnt[tid];
    sc[tid] = v;
    __syncthreads();
    for (int off = 1; off < 256; off <<= 1) {
        int t = (tid >= off) ? sc[tid - off] : 0;
        __syncthreads();
        sc[tid] += t;
        __syncthreads();
    }
    int excl = sc[tid] - v;
    cur[tid] = excl;
    if (node < N_NODES) row_start[node] = e0 + excl;
    __syncthreads();
    for (int i = e0 + tid; i < e1; i += 256) {
        int d = edst[i];
        uint2 sw = esw[i];
        int ld = d & 255;
        int p = e0 + atomicAdd(&cur[ld], 1);  // LDS atomic
        float nv = -dinv[sw.x] * __uint_as_float(sw.y) * ldinv[ld];
        uint2 r; r.x = sw.x; r.y = __float_as_uint(nv);
        csr[p] = r;
    }
}

// copy x (50000x128 fp32) into Th slice 0 (f16, row stride 384)
__global__ void k_copy_x(const float* __restrict__ x, __half* __restrict__ Th, int n2) {
    int i = blockIdx.x * blockDim.x + threadIdx.x;  // half2 index
    if (i < n2) {
        int node = i >> 6;
        int c2 = (i & 63) * 2;
        float2 v = *(const float2*)&x[(size_t)node * 128 + c2];
        *(__half2*)&Th[(size_t)node * 384 + c2] = __floats2half2_rn(v.x, v.y);
    }
}

// W (384 x C fp32) -> Wt (C x 384 f16), Wt[n*384+k] = W[k*C+n]
__global__ void k_wt(const float* __restrict__ W, __half* __restrict__ Wt, int C) {
    int i = blockIdx.x * blockDim.x + threadIdx.x;
    if (i < C * 384) {
        int n = i / 384, k = i % 384;
        Wt[i] = __float2half(W[(size_t)k * C + n]);
    }
}

// ---------- SpMM: one wave per node, lane owns 2 f16 features ----------
// unrolled x8 (keeps 8 gathers in flight to cover L2/LLC latency)
__global__ __launch_bounds__(256) void k_spmm(__half* Th, const int* __restrict__ row_start,
                                              const uint2* __restrict__ csr,
                                              int in_off, int out_off, int mode) {
    int node = blockIdx.x * 4 + (threadIdx.x >> 6);
    int lane = threadIdx.x & 63;
    int s = row_start[node];
    int e = row_start[node + 1];
    const __half* Tin = Th + in_off + 2 * lane;
    float ax0 = 0.f, ay0 = 0.f, ax1 = 0.f, ay1 = 0.f;
    float ax2 = 0.f, ay2 = 0.f, ax3 = 0.f, ay3 = 0.f;
    float ax4 = 0.f, ay4 = 0.f, ax5 = 0.f, ay5 = 0.f;
    float ax6 = 0.f, ay6 = 0.f, ax7 = 0.f, ay7 = 0.f;
    int j = s;
    for (; j + 8 <= e; j += 8) {
        uint2 e0 = csr[j + 0], e1 = csr[j + 1], e2 = csr[j + 2], e3 = csr[j + 3];
        uint2 e4 = csr[j + 4], e5 = csr[j + 5], e6 = csr[j + 6], e7 = csr[j + 7];
        __half2 r0 = *(const __half2*)&Tin[(size_t)e0.x * 384];
        __half2 r1 = *(const __half2*)&Tin[(size_t)e1.x * 384];
        __half2 r2 = *(const __half2*)&Tin[(size_t)e2.x * 384];
        __half2 r3 = *(const __half2*)&Tin[(size_t)e3.x * 384];
        __half2 r4 = *(const __half2*)&Tin[(size_t)e4.x * 384];
        __half2 r5 = *(const __half2*)&Tin[(size_t)e5.x * 384];
        __half2 r6 = *(const __half2*)&Tin[(size_t)e6.x * 384];
        __half2 r7 = *(const __half2*)&Tin[(size_t)e7.x * 384];
        float2 f0 = __half22float2(r0), f1 = __half22float2(r1);
        float2 f2 = __half22float2(r2), f3 = __half22float2(r3);
        float2 f4 = __half22float2(r4), f5 = __half22float2(r5);
        float2 f6 = __half22float2(r6), f7 = __half22float2(r7);
        float n0 = __uint_as_float(e0.y), n1 = __uint_as_float(e1.y);
        float n2 = __uint_as_float(e2.y), n3 = __uint_as_float(e3.y);
        float n4 = __uint_as_float(e4.y), n5 = __uint_as_float(e5.y);
        float n6 = __uint_as_float(e6.y), n7 = __uint_as_float(e7.y);
        ax0 = fmaf(n0, f0.x, ax0); ay0 = fmaf(n0, f0.y, ay0);
        ax1 = fmaf(n1, f1.x, ax1); ay1 = fmaf(n1, f1.y, ay1);
        ax2 = fmaf(n2, f2.x, ax2); ay2 = fmaf(n2, f2.y, ay2);
        ax3 = fmaf(n3, f3.x, ax3); ay3 = fmaf(n3, f3.y, ay3);
        ax4 = fmaf(n4, f4.x, ax4); ay4 = fmaf(n4, f4.y, ay4);
        ax5 = fmaf(n5, f5.x, ax5); ay5 = fmaf(n5, f5.y, ay5);
        ax6 = fmaf(n6, f6.x, ax6); ay6 = fmaf(n6, f6.y, ay6);
        ax7 = fmaf(n7, f7.x, ax7); ay7 = fmaf(n7, f7.y, ay7);
    }
    for (; j < e; j++) {
        uint2 ee = csr[j];
        __half2 r = *(const __half2*)&Tin[(size_t)ee.x * 384];
        float2 f = __half22float2(r);
        float nv = __uint_as_float(ee.y);
        ax0 = fmaf(nv, f.x, ax0); ay0 = fmaf(nv, f.y, ay0);
    }
    float ax = ((ax0 + ax1) + (ax2 + ax3)) + ((ax4 + ax5) + (ax6 + ax7));
    float ay = ((ay0 + ay1) + (ay2 + ay3)) + ((ay4 + ay5) + (ay6 + ay7));
    float ox = ax, oy = ay;
    if (mode) {
        __half2 t0h = *(const __half2*)&Th[(size_t)node * 384 + 2 * lane];
        float2 t0 = __half22float2(t0h);
        ox = 2.f * ax - t0.x;
        oy = 2.f * ay - t0.y;
    }
    *(__half2*)&Th[(size_t)node * 384 + out_off + 2 * lane] = __floats2half2_rn(ox, oy);
}

// ---------- MFMA GEMM: out = sigmoid(A[Mx384 f16] @ Wt^T[384xC f16] + b) ----------
// mfma_f32_16x16x32_f16: A[m=lane&15][k=(lane>>4)*8+j]; C/D col=lane&15,row=(lane>>4)*4+r.
// A and out may alias (rows owned exclusively per block) -> no __restrict__.
template <int C>
__global__ __launch_bounds__(256) void k_gemm(const __half* A, const __half* __restrict__ Wt,
                                              const float* __restrict__ bias, void* out,
                                              int mode, int M) {
    constexpr int NF = C / 16;
    __shared__ _Float16 As[64][56];
    __shared__ _Float16 Bs[C][56];
    int tid = threadIdx.x;
    int wave = tid >> 6, lane = tid & 63;
    int lm = lane & 15, lq = lane >> 4;
    int m0 = blockIdx.x * 64;
    f32x4 acc[NF];
    for (int nf = 0; nf < NF; nf++) acc[nf] = (f32x4)0.0f;

    for (int k0 = 0; k0 < 384; k0 += 32) {
        {
            int r = tid >> 2, q = tid & 3;
            int row = m0 + r;
            if (row >= M) row = M - 1;
            *(f16x8*)&As[r][q * 8] = *(const f16x8*)&A[(size_t)row * 384 + k0 + q * 8];
        }
        for (int i = 0; i < (C * 4) / 256; i++) {
            int idx = tid + i * 256;
            int n = idx >> 2, q = idx & 3;
            *(f16x8*)&Bs[n][q * 8] = *(const f16x8*)&Wt[(size_t)n * 384 + k0 + q * 8];
        }
        __syncthreads();
        f16x8 a = *(const f16x8*)&As[wave * 16 + lm][lq * 8];
        for (int nf = 0; nf < NF; nf++) {
            f16x8 b = *(const f16x8*)&Bs[nf * 16 + lm][lq * 8];
            acc[nf] = __builtin_amdgcn_mfma_f32_16x16x32_f16(a, b, acc[nf], 0, 0, 0);
        }
        __syncthreads();
    }
    for (int nf = 0; nf < NF; nf++) {
        for (int r = 0; r < 4; r++) {
            int grow = m0 + wave * 16 + lq * 4 + r;
            int col = nf * 16 + lm;
            if (grow < M) {
                float v = acc[nf][r] + bias[col];
                v = 1.f / (1.f + expf(-v));
                if (mode == 0)
                    ((__half*)out)[(size_t)grow * 384 + col] = __float2half(v);
                else
                    ((float*)out)[(size_t)grow * C + col] = v;
            }
        }
    }
}

extern "C" void kernel_launch(void* const* d_in, const int* in_sizes, int n_in,
                              void* d_out, int out_size, void* d_ws, size_t ws_size,
                              hipStream_t stream) {
    const float* x  = (const float*)d_in[0];
    const int*   ei = (const int*)d_in[1];
    const float* ew = (const float*)d_in[2];
    const float* W0 = (const float*)d_in[3];
    const float* b0 = (const float*)d_in[4];
    const float* W1 = (const float*)d_in[5];
    const float* b1 = (const float*)d_in[6];
    const float* W2 = (const float*)d_in[7];
    const float* b2 = (const float*)d_in[8];
    const int* src = ei;
    const int* dst = ei + N_EDGES;

    char* ws = (char*)d_ws;
    size_t off = 0;
    auto alloc = [&](size_t bytes) -> char* {
        size_t p = (off + 255) & ~(size_t)255;
        off = p + bytes;
        return ws + p;
    };
    __half* Th        = (__half*)alloc((size_t)N_NODES * 384 * 2);     // [T0|T1|T2] f16
    uint2*  csr       = (uint2*)alloc((size_t)N_EDGES * 8);            // (src, norm)
    int*    edst      = (int*)alloc((size_t)N_EDGES * 4);              // bucket-sorted dst
    uint2*  esw       = (uint2*)alloc((size_t)N_EDGES * 8);            // bucket-sorted (src,w)
    int*    bcnt      = (int*)alloc((size_t)EBLK * 256 * 4);
    int*    bucket_start = (int*)alloc(257 * 4);
    int*    row_start = (int*)alloc((size_t)(N_NODES + 1) * 4);
    float*  deg       = (float*)alloc((size_t)N_NODES * 4);            // deg -> dinv in place
    __half* Wt0       = (__half*)alloc((size_t)128 * 384 * 2);
    __half* Wt1       = (__half*)alloc((size_t)128 * 384 * 2);
    __half* Wt2       = (__half*)alloc((size_t)64 * 384 * 2);

    hipMemsetAsync(deg, 0, N_NODES * 4, stream);

    // bucket sort by dst; deg atomics fused into the scatter pass
    k_bcount<<<EBLK, 256, 0, stream>>>(dst, bcnt);
    k_bscan<<<1, 256, 0, stream>>>(bcnt, bucket_start, row_start);
    k_bscatter<<<EBLK, 256, 0, stream>>>(src, dst, ew, bcnt, edst, esw, deg);
    k_dinv<<<(N_NODES + 255) / 256, 256, 0, stream>>>(deg, N_NODES);
    // final CSR + inline norm
    k_bcsr<<<NBUCK, 256, 0, stream>>>(edst, esw, bucket_start, deg, row_start, csr);

    k_copy_x<<<(N_NODES * 64 + 255) / 256, 256, 0, stream>>>(x, Th, N_NODES * 64);
    k_wt<<<(128 * 384 + 255) / 256, 256, 0, stream>>>(W0, Wt0, 128);
    k_wt<<<(128 * 384 + 255) / 256, 256, 0, stream>>>(W1, Wt1, 128);
    k_wt<<<(64 * 384 + 255) / 256, 256, 0, stream>>>(W2, Wt2, 64);

    const __half* Wl[3] = {Wt0, Wt1, Wt2};
    const float*  bl[3] = {b0, b1, b2};
    int gemm_blocks = (N_NODES + 63) / 64;
    for (int l = 0; l < 3; l++) {
        k_spmm<<<N_NODES / 4, 256, 0, stream>>>(Th, row_start, csr, 0, 128, 0);
        k_spmm<<<N_NODES / 4, 256, 0, stream>>>(Th, row_start, csr, 128, 256, 1);
        if (l < 2)
            k_gemm<128><<<gemm_blocks, 256, 0, stream>>>(Th, Wl[l], bl[l], Th, 0, N_NODES);
        else
            k_gemm<64><<<gemm_blocks, 256, 0, stream>>>(Th, Wl[l], bl[l], d_out, 1, N_NODES);
    }
}

// Round 6
// 627.481 us; speedup vs baseline: 1.8610x; 1.0586x over previous
//
#include <hip/hip_runtime.h>
#include <hip/hip_fp16.h>
#include <math.h>

#define N_NODES 50000
#define N_EDGES 1600000
#define NBUCK 196          // node >> 8 buckets (50000/256)
#define EBLK 400           // edge blocks for sort
#define CHUNK 4000         // edges per block (EBLK*CHUNK == N_EDGES)

typedef _Float16 f16x8 __attribute__((ext_vector_type(8)));
typedef float f32x4 __attribute__((ext_vector_type(4)));

// ---------- dual bucket sort (dst-keyed for CSR, src-keyed for deg) ----------
// Phase A: per-(edge-block, bucket) counts for BOTH keys via LDS histograms
__global__ __launch_bounds__(256) void k_bcount(const int* __restrict__ src,
                                                const int* __restrict__ dst,
                                                int* __restrict__ bcnt_d,
                                                int* __restrict__ bcnt_s) {
    __shared__ int lcd[256];
    __shared__ int lcs[256];
    int tid = threadIdx.x;
    lcd[tid] = 0; lcs[tid] = 0;
    __syncthreads();
    int base = blockIdx.x * CHUNK;
    for (int i = tid; i < CHUNK; i += 256) {
        atomicAdd(&lcd[dst[base + i] >> 8], 1);
        atomicAdd(&lcs[src[base + i] >> 8], 1);
    }
    __syncthreads();
    bcnt_d[blockIdx.x * 256 + tid] = lcd[tid];
    bcnt_s[blockIdx.x * 256 + tid] = lcs[tid];
}

// Phase B: bucket-major exclusive scans of bcnt_d/bcnt_s [EBLK][256] (1 block)
__global__ __launch_bounds__(256) void k_bscan(int* __restrict__ bcnt_d,
                                               int* __restrict__ bcnt_s,
                                               int* __restrict__ bstart_d,
                                               int* __restrict__ bstart_s,
                                               int* __restrict__ row_start) {
    int b = threadIdx.x;
    int run_d = 0, run_s = 0;
    for (int k = 0; k < EBLK; k++) {
        int t = bcnt_d[k * 256 + b]; bcnt_d[k * 256 + b] = run_d; run_d += t;
        int u = bcnt_s[k * 256 + b]; bcnt_s[k * 256 + b] = run_s; run_s += u;
    }
    __shared__ int s[256];
    // scan dst totals
    s[b] = run_d;
    __syncthreads();
    for (int off = 1; off < 256; off <<= 1) {
        int t = (b >= off) ? s[b - off] : 0;
        __syncthreads();
        s[b] += t;
        __syncthreads();
    }
    int dstart = s[b] - run_d;
    __syncthreads();
    // scan src totals
    s[b] = run_s;
    __syncthreads();
    for (int off = 1; off < 256; off <<= 1) {
        int t = (b >= off) ? s[b - off] : 0;
        __syncthreads();
        s[b] += t;
        __syncthreads();
    }
    int sstart = s[b] - run_s;
    bstart_d[b] = dstart;
    bstart_s[b] = sstart;
    if (b == 0) {
        bstart_d[256] = N_EDGES;
        bstart_s[256] = N_EDGES;
        row_start[N_NODES] = N_EDGES;
    }
    for (int k = 0; k < EBLK; k++) {
        bcnt_d[k * 256 + b] += dstart;
        bcnt_s[k * 256 + b] += sstart;
    }
}

// Phase C: scatter packed records into both sorted orders (LDS cursors only).
// dsw: {lo = src | (dst&255)<<16, hi = w}  (src < 2^16)
// ssw: {lo = src&255,             hi = w}
__global__ __launch_bounds__(256) void k_bscatter(const int* __restrict__ src,
                                                  const int* __restrict__ dst,
                                                  const float* __restrict__ w,
                                                  const int* __restrict__ bcnt_d,
                                                  const int* __restrict__ bcnt_s,
                                                  uint2* __restrict__ dsw,
                                                  uint2* __restrict__ ssw) {
    __shared__ int curd[256];
    __shared__ int curs[256];
    int tid = threadIdx.x;
    curd[tid] = bcnt_d[blockIdx.x * 256 + tid];
    curs[tid] = bcnt_s[blockIdx.x * 256 + tid];
    __syncthreads();
    int base = blockIdx.x * CHUNK;
    for (int i = tid; i < CHUNK; i += 256) {
        int d = dst[base + i];
        int ss = src[base + i];
        float wi = w[base + i];
        unsigned wb = __float_as_uint(wi);
        int p = atomicAdd(&curd[d >> 8], 1);   // LDS atomic
        uint2 r; r.x = (unsigned)ss | ((unsigned)(d & 255) << 16); r.y = wb;
        dsw[p] = r;
        int q = atomicAdd(&curs[ss >> 8], 1);  // LDS atomic
        uint2 r2; r2.x = (unsigned)(ss & 255); r2.y = wb;
        ssw[q] = r2;
    }
}

// deg per src-bucket: LDS float accumulate, then dinv = rsqrt(deg) in place
__global__ __launch_bounds__(256) void k_sdeg(const uint2* __restrict__ ssw,
                                              const int* __restrict__ bstart_s,
                                              float* __restrict__ dinv) {
    __shared__ float h[256];
    int tid = threadIdx.x;
    int b = blockIdx.x;
    h[tid] = 0.f;
    __syncthreads();
    int e0 = bstart_s[b], e1 = bstart_s[b + 1];
    for (int i = e0 + tid; i < e1; i += 256) {
        uint2 r = ssw[i];
        atomicAdd(&h[r.x & 255], __uint_as_float(r.y));  // LDS atomic
    }
    __syncthreads();
    int node = (b << 8) + tid;
    if (node < N_NODES) {
        float d = h[tid];
        dinv[node] = d > 0.f ? rsqrtf(fmaxf(d, 1e-30f)) : 0.f;
    }
}

// Phase D: per-bucket CSR build + inline norm (one block per dst-bucket)
__global__ __launch_bounds__(256) void k_bcsr(const uint2* __restrict__ dsw,
                                              const int* __restrict__ bstart_d,
                                              const float* __restrict__ dinv,
                                              int* __restrict__ row_start,
                                              uint2* __restrict__ csr) {
    __shared__ int ncnt[256];
    __shared__ int cur[256];
    __shared__ int sc[256];
    __shared__ float ldinv[256];
    int tid = threadIdx.x;
    int b = blockIdx.x;
    int node = (b << 8) + tid;
    ncnt[tid] = 0;
    ldinv[tid] = (node < N_NODES) ? dinv[node] : 0.f;
    __syncthreads();
    int e0 = bstart_d[b], e1 = bstart_d[b + 1];
    for (int i = e0 + tid; i < e1; i += 256)
        atomicAdd(&ncnt[(dsw[i].x >> 16) & 255], 1);  // LDS atomic
    __syncthreads();
    int v = ncnt[tid];
    sc[tid] = v;
    __syncthreads();
    for (int off = 1; off < 256; off <<= 1) {
        int t = (tid >= off) ? sc[tid - off] : 0;
        __syncthreads();
        sc[tid] += t;
        __syncthreads();
    }
    int excl = sc[tid] - v;
    cur[tid] = excl;
    if (node < N_NODES) row_start[node] = e0 + excl;
    __syncthreads();
    for (int i = e0 + tid; i < e1; i += 256) {
        uint2 sw = dsw[i];
        int srcn = sw.x & 0xFFFF;
        int ld = (sw.x >> 16) & 255;
        int p = e0 + atomicAdd(&cur[ld], 1);  // LDS atomic
        float nv = -dinv[srcn] * __uint_as_float(sw.y) * ldinv[ld];
        uint2 r; r.x = (unsigned)srcn; r.y = __float_as_uint(nv);
        csr[p] = r;
    }
}

// copy x (50000x128 fp32) into Th slice 0 (f16, row stride 384)
__global__ void k_copy_x(const float* __restrict__ x, __half* __restrict__ Th, int n2) {
    int i = blockIdx.x * blockDim.x + threadIdx.x;  // half2 index
    if (i < n2) {
        int node = i >> 6;
        int c2 = (i & 63) * 2;
        float2 v = *(const float2*)&x[(size_t)node * 128 + c2];
        *(__half2*)&Th[(size_t)node * 384 + c2] = __floats2half2_rn(v.x, v.y);
    }
}

// Build adjusted transposed weights (folds Chebyshev recombination):
// out = T0*(W0-W2) + T1*W1 + U*(2*W2), U = L*T1   [T2 = 2U - T0 never formed]
// W (384 x C fp32, k = kcheb*128 + cin) -> Wt (C x 384 f16)
__global__ void k_wt(const float* __restrict__ W, __half* __restrict__ Wt, int C) {
    int i = blockIdx.x * blockDim.x + threadIdx.x;
    if (i < C * 384) {
        int n = i / 384, k = i % 384;
        int kc = k >> 7, cin = k & 127;
        float v;
        if (kc == 0)      v = W[(size_t)k * C + n] - W[(size_t)(256 + cin) * C + n];
        else if (kc == 1) v = W[(size_t)k * C + n];
        else              v = 2.f * W[(size_t)k * C + n];
        Wt[i] = __float2half(v);
    }
}

// ---------- SpMM: one wave per node, lane owns 2 f16 features ----------
// Cooperative csr load: lanes 0..7 hold entries j..j+7 (one 64B line per 8
// edges instead of 8 wave-uniform loads), broadcast via shfl; 8 independent
// gathers in flight to cover L2/LLC latency.
__global__ __launch_bounds__(256) void k_spmm(__half* Th, const int* __restrict__ row_start,
                                              const uint2* __restrict__ csr,
                                              int in_off, int out_off) {
    int node = blockIdx.x * 4 + (threadIdx.x >> 6);
    int lane = threadIdx.x & 63;
    int s = row_start[node];
    int e = row_start[node + 1];
    const __half* Tin = Th + in_off + 2 * lane;
    float ax[8], ay[8];
    #pragma unroll
    for (int k = 0; k < 8; k++) { ax[k] = 0.f; ay[k] = 0.f; }
    int j = s;
    for (; j + 8 <= e; j += 8) {
        uint2 mye = csr[j + (lane & 7)];
        int sp[8]; float nv[8];
        #pragma unroll
        for (int k = 0; k < 8; k++) {
            sp[k] = __shfl((int)mye.x, k);
            nv[k] = __uint_as_float(__shfl((int)mye.y, k));
        }
        __half2 r[8];
        #pragma unroll
        for (int k = 0; k < 8; k++)
            r[k] = *(const __half2*)&Tin[(size_t)sp[k] * 384];
        #pragma unroll
        for (int k = 0; k < 8; k++) {
            float2 f = __half22float2(r[k]);
            ax[k] = fmaf(nv[k], f.x, ax[k]);
            ay[k] = fmaf(nv[k], f.y, ay[k]);
        }
    }
    for (; j < e; j++) {
        uint2 ee = csr[j];
        __half2 r = *(const __half2*)&Tin[(size_t)(ee.x & 0xFFFFFFFF) * 384];
        float2 f = __half22float2(r);
        float nvv = __uint_as_float(ee.y);
        ax[0] = fmaf(nvv, f.x, ax[0]); ay[0] = fmaf(nvv, f.y, ay[0]);
    }
    float axs = ((ax[0] + ax[1]) + (ax[2] + ax[3])) + ((ax[4] + ax[5]) + (ax[6] + ax[7]));
    float ays = ((ay[0] + ay[1]) + (ay[2] + ay[3])) + ((ay[4] + ay[5]) + (ay[6] + ay[7]));
    *(__half2*)&Th[(size_t)node * 384 + out_off + 2 * lane] = __floats2half2_rn(axs, ays);
}

// ---------- MFMA GEMM: out = sigmoid(A[Mx384 f16] @ Wt^T[384xC f16] + b) ----------
// mfma_f32_16x16x32_f16: A[m=lane&15][k=(lane>>4)*8+j]; C/D col=lane&15,row=(lane>>4)*4+r.
// A and out may alias (rows owned exclusively per block) -> no __restrict__.
template <int C>
__global__ __launch_bounds__(256) void k_gemm(const __half* A, const __half* __restrict__ Wt,
                                              const float* __restrict__ bias, void* out,
                                              int mode, int M) {
    constexpr int NF = C / 16;
    __shared__ _Float16 As[64][56];
    __shared__ _Float16 Bs[C][56];
    int tid = threadIdx.x;
    int wave = tid >> 6, lane = tid & 63;
    int lm = lane & 15, lq = lane >> 4;
    int m0 = blockIdx.x * 64;
    f32x4 acc[NF];
    for (int nf = 0; nf < NF; nf++) acc[nf] = (f32x4)0.0f;

    for (int k0 = 0; k0 < 384; k0 += 32) {
        {
            int r = tid >> 2, q = tid & 3;
            int row = m0 + r;
            if (row >= M) row = M - 1;
            *(f16x8*)&As[r][q * 8] = *(const f16x8*)&A[(size_t)row * 384 + k0 + q * 8];
        }
        for (int i = 0; i < (C * 4) / 256; i++) {
            int idx = tid + i * 256;
            int n = idx >> 2, q = idx & 3;
            *(f16x8*)&Bs[n][q * 8] = *(const f16x8*)&Wt[(size_t)n * 384 + k0 + q * 8];
        }
        __syncthreads();
        f16x8 a = *(const f16x8*)&As[wave * 16 + lm][lq * 8];
        for (int nf = 0; nf < NF; nf++) {
            f16x8 b = *(const f16x8*)&Bs[nf * 16 + lm][lq * 8];
            acc[nf] = __builtin_amdgcn_mfma_f32_16x16x32_f16(a, b, acc[nf], 0, 0, 0);
        }
        __syncthreads();
    }
    for (int nf = 0; nf < NF; nf++) {
        for (int r = 0; r < 4; r++) {
            int grow = m0 + wave * 16 + lq * 4 + r;
            int col = nf * 16 + lm;
            if (grow < M) {
                float v = acc[nf][r] + bias[col];
                v = 1.f / (1.f + expf(-v));
                if (mode == 0)
                    ((__half*)out)[(size_t)grow * 384 + col] = __float2half(v);
                else
                    ((float*)out)[(size_t)grow * C + col] = v;
            }
        }
    }
}

extern "C" void kernel_launch(void* const* d_in, const int* in_sizes, int n_in,
                              void* d_out, int out_size, void* d_ws, size_t ws_size,
                              hipStream_t stream) {
    const float* x  = (const float*)d_in[0];
    const int*   ei = (const int*)d_in[1];
    const float* ew = (const float*)d_in[2];
    const float* W0 = (const float*)d_in[3];
    const float* b0 = (const float*)d_in[4];
    const float* W1 = (const float*)d_in[5];
    const float* b1 = (const float*)d_in[6];
    const float* W2 = (const float*)d_in[7];
    const float* b2 = (const float*)d_in[8];
    const int* src = ei;
    const int* dst = ei + N_EDGES;

    char* ws = (char*)d_ws;
    size_t off = 0;
    auto alloc = [&](size_t bytes) -> char* {
        size_t p = (off + 255) & ~(size_t)255;
        off = p + bytes;
        return ws + p;
    };
    __half* Th      = (__half*)alloc((size_t)N_NODES * 384 * 2);   // [T0|T1|U] f16
    uint2*  csr     = (uint2*)alloc((size_t)N_EDGES * 8);          // (src, norm)
    uint2*  dsw     = (uint2*)alloc((size_t)N_EDGES * 8);          // dst-sorted (src|dl, w)
    uint2*  ssw     = (uint2*)alloc((size_t)N_EDGES * 8);          // src-sorted (sl, w)
    int*    bcnt_d  = (int*)alloc((size_t)EBLK * 256 * 4);
    int*    bcnt_s  = (int*)alloc((size_t)EBLK * 256 * 4);
    int*    bstart_d= (int*)alloc(257 * 4);
    int*    bstart_s= (int*)alloc(257 * 4);
    int*    row_start = (int*)alloc((size_t)(N_NODES + 1) * 4);
    float*  dinv    = (float*)alloc((size_t)N_NODES * 4);
    __half* Wt0     = (__half*)alloc((size_t)128 * 384 * 2);
    __half* Wt1     = (__half*)alloc((size_t)128 * 384 * 2);
    __half* Wt2     = (__half*)alloc((size_t)64 * 384 * 2);

    // dual bucket sort; zero device-scope atomics anywhere
    k_bcount<<<EBLK, 256, 0, stream>>>(src, dst, bcnt_d, bcnt_s);
    k_bscan<<<1, 256, 0, stream>>>(bcnt_d, bcnt_s, bstart_d, bstart_s, row_start);
    k_bscatter<<<EBLK, 256, 0, stream>>>(src, dst, ew, bcnt_d, bcnt_s, dsw, ssw);
    k_sdeg<<<NBUCK, 256, 0, stream>>>(ssw, bstart_s, dinv);
    k_bcsr<<<NBUCK, 256, 0, stream>>>(dsw, bstart_d, dinv, row_start, csr);

    k_copy_x<<<(N_NODES * 64 + 255) / 256, 256, 0, stream>>>(x, Th, N_NODES * 64);
    k_wt<<<(128 * 384 + 255) / 256, 256, 0, stream>>>(W0, Wt0, 128);
    k_wt<<<(128 * 384 + 255) / 256, 256, 0, stream>>>(W1, Wt1, 128);
    k_wt<<<(64 * 384 + 255) / 256, 256, 0, stream>>>(W2, Wt2, 64);

    const __half* Wl[3] = {Wt0, Wt1, Wt2};
    const float*  bl[3] = {b0, b1, b2};
    int gemm_blocks = (N_NODES + 63) / 64;
    for (int l = 0; l < 3; l++) {
        k_spmm<<<N_NODES / 4, 256, 0, stream>>>(Th, row_start, csr, 0, 128);    // T1 = L*T0
        k_spmm<<<N_NODES / 4, 256, 0, stream>>>(Th, row_start, csr, 128, 256);  // U  = L*T1
        if (l < 2)
            k_gemm<128><<<gemm_blocks, 256, 0, stream>>>(Th, Wl[l], bl[l], Th, 0, N_NODES);
        else
            k_gemm<64><<<gemm_blocks, 256, 0, stream>>>(Th, Wl[l], bl[l], d_out, 1, N_NODES);
    }
}

// Round 7
// 554.917 us; speedup vs baseline: 2.1044x; 1.1308x over previous
//
#include <hip/hip_runtime.h>
#include <hip/hip_fp16.h>
#include <math.h>

#define N_NODES 50000
#define N_EDGES 1600000
#define NBUCK 196          // node >> 8 buckets (50000/256)
#define EBLK 400           // edge blocks for sort
#define CHUNK 4000         // edges per block (EBLK*CHUNK == N_EDGES)

typedef _Float16 f16x8 __attribute__((ext_vector_type(8)));
typedef float f32x4 __attribute__((ext_vector_type(4)));

// ---------- dual bucket sort (dst-keyed for CSR, src-keyed for deg) ----------
// Phase A: per-(edge-block, bucket) counts for BOTH keys via LDS histograms
__global__ __launch_bounds__(256) void k_bcount(const int* __restrict__ src,
                                                const int* __restrict__ dst,
                                                int* __restrict__ bcnt_d,
                                                int* __restrict__ bcnt_s) {
    __shared__ int lcd[256];
    __shared__ int lcs[256];
    int tid = threadIdx.x;
    lcd[tid] = 0; lcs[tid] = 0;
    __syncthreads();
    int base = blockIdx.x * CHUNK;
    for (int i = tid; i < CHUNK; i += 256) {
        atomicAdd(&lcd[dst[base + i] >> 8], 1);
        atomicAdd(&lcs[src[base + i] >> 8], 1);
    }
    __syncthreads();
    bcnt_d[blockIdx.x * 256 + tid] = lcd[tid];
    bcnt_s[blockIdx.x * 256 + tid] = lcs[tid];
}

// Phase B1: per-bucket scan over edge-blocks (parallel; replaces the serial
// single-block k_bscan that cost 57us at EBLK=400). Grid = 512: bucket b =
// blockIdx&255, array = blockIdx>>8. Thread t owns k = 2t, 2t+1.
__global__ __launch_bounds__(256) void k_bscan1(int* __restrict__ bcnt_d,
                                                int* __restrict__ bcnt_s,
                                                int* __restrict__ btot) {
    int b = blockIdx.x & 255;
    int* bcnt = (blockIdx.x >> 8) ? bcnt_s : bcnt_d;
    int tid = threadIdx.x;
    int k0 = 2 * tid;
    int v0 = (k0 < EBLK) ? bcnt[k0 * 256 + b] : 0;
    int v1 = (k0 + 1 < EBLK) ? bcnt[(k0 + 1) * 256 + b] : 0;
    int pair = v0 + v1;
    __shared__ int s[256];
    s[tid] = pair;
    __syncthreads();
    for (int off = 1; off < 256; off <<= 1) {
        int t = (tid >= off) ? s[tid - off] : 0;
        __syncthreads();
        s[tid] += t;
        __syncthreads();
    }
    int excl = s[tid] - pair;
    if (k0 < EBLK)     bcnt[k0 * 256 + b] = excl;
    if (k0 + 1 < EBLK) bcnt[(k0 + 1) * 256 + b] = excl + v0;
    if (tid == 255) btot[(blockIdx.x >> 8) * 256 + b] = s[255];
}

// Phase B2: scan the 256 bucket totals for both arrays (1 block)
__global__ __launch_bounds__(256) void k_bscan2(const int* __restrict__ btot,
                                                int* __restrict__ bstart_d,
                                                int* __restrict__ bstart_s,
                                                int* __restrict__ row_start) {
    __shared__ int s[256];
    int b = threadIdx.x;
    int v = btot[b];
    s[b] = v;
    __syncthreads();
    for (int off = 1; off < 256; off <<= 1) {
        int t = (b >= off) ? s[b - off] : 0;
        __syncthreads();
        s[b] += t;
        __syncthreads();
    }
    bstart_d[b] = s[b] - v;
    if (b == 0) {
        bstart_d[256] = N_EDGES;
        row_start[N_NODES] = N_EDGES;
    }
    __syncthreads();
    int v2 = btot[256 + b];
    s[b] = v2;
    __syncthreads();
    for (int off = 1; off < 256; off <<= 1) {
        int t = (b >= off) ? s[b - off] : 0;
        __syncthreads();
        s[b] += t;
        __syncthreads();
    }
    bstart_s[b] = s[b] - v2;
    if (b == 0) bstart_s[256] = N_EDGES;
}

// Phase C: scatter packed records into both sorted orders (LDS cursors only).
// Cursor = per-block exclusive offset within bucket + bucket start.
// dsw: {lo = src | (dst&255)<<16, hi = w}  (src < 2^16)
// ssw: {lo = src&255,             hi = w}
__global__ __launch_bounds__(256) void k_bscatter(const int* __restrict__ src,
                                                  const int* __restrict__ dst,
                                                  const float* __restrict__ w,
                                                  const int* __restrict__ bcnt_d,
                                                  const int* __restrict__ bcnt_s,
                                                  const int* __restrict__ bstart_d,
                                                  const int* __restrict__ bstart_s,
                                                  uint2* __restrict__ dsw,
                                                  uint2* __restrict__ ssw) {
    __shared__ int curd[256];
    __shared__ int curs[256];
    int tid = threadIdx.x;
    curd[tid] = bcnt_d[blockIdx.x * 256 + tid] + bstart_d[tid];
    curs[tid] = bcnt_s[blockIdx.x * 256 + tid] + bstart_s[tid];
    __syncthreads();
    int base = blockIdx.x * CHUNK;
    for (int i = tid; i < CHUNK; i += 256) {
        int d = dst[base + i];
        int ss = src[base + i];
        float wi = w[base + i];
        unsigned wb = __float_as_uint(wi);
        int p = atomicAdd(&curd[d >> 8], 1);   // LDS atomic
        uint2 r; r.x = (unsigned)ss | ((unsigned)(d & 255) << 16); r.y = wb;
        dsw[p] = r;
        int q = atomicAdd(&curs[ss >> 8], 1);  // LDS atomic
        uint2 r2; r2.x = (unsigned)(ss & 255); r2.y = wb;
        ssw[q] = r2;
    }
}

// deg per src-bucket: LDS float accumulate, then dinv = rsqrt(deg) in place
__global__ __launch_bounds__(256) void k_sdeg(const uint2* __restrict__ ssw,
                                              const int* __restrict__ bstart_s,
                                              float* __restrict__ dinv) {
    __shared__ float h[256];
    int tid = threadIdx.x;
    int b = blockIdx.x;
    h[tid] = 0.f;
    __syncthreads();
    int e0 = bstart_s[b], e1 = bstart_s[b + 1];
    for (int i = e0 + tid; i < e1; i += 256) {
        uint2 r = ssw[i];
        atomicAdd(&h[r.x & 255], __uint_as_float(r.y));  // LDS atomic
    }
    __syncthreads();
    int node = (b << 8) + tid;
    if (node < N_NODES) {
        float d = h[tid];
        dinv[node] = d > 0.f ? rsqrtf(fmaxf(d, 1e-30f)) : 0.f;
    }
}

// Phase D: per-bucket CSR build + inline norm (one block per dst-bucket)
__global__ __launch_bounds__(256) void k_bcsr(const uint2* __restrict__ dsw,
                                              const int* __restrict__ bstart_d,
                                              const float* __restrict__ dinv,
                                              int* __restrict__ row_start,
                                              uint2* __restrict__ csr) {
    __shared__ int ncnt[256];
    __shared__ int cur[256];
    __shared__ int sc[256];
    __shared__ float ldinv[256];
    int tid = threadIdx.x;
    int b = blockIdx.x;
    int node = (b << 8) + tid;
    ncnt[tid] = 0;
    ldinv[tid] = (node < N_NODES) ? dinv[node] : 0.f;
    __syncthreads();
    int e0 = bstart_d[b], e1 = bstart_d[b + 1];
    for (int i = e0 + tid; i < e1; i += 256)
        atomicAdd(&ncnt[(dsw[i].x >> 16) & 255], 1);  // LDS atomic
    __syncthreads();
    int v = ncnt[tid];
    sc[tid] = v;
    __syncthreads();
    for (int off = 1; off < 256; off <<= 1) {
        int t = (tid >= off) ? sc[tid - off] : 0;
        __syncthreads();
        sc[tid] += t;
        __syncthreads();
    }
    int excl = sc[tid] - v;
    cur[tid] = excl;
    if (node < N_NODES) row_start[node] = e0 + excl;
    __syncthreads();
    for (int i = e0 + tid; i < e1; i += 256) {
        uint2 sw = dsw[i];
        int srcn = sw.x & 0xFFFF;
        int ld = (sw.x >> 16) & 255;
        int p = e0 + atomicAdd(&cur[ld], 1);  // LDS atomic
        float nv = -dinv[srcn] * __uint_as_float(sw.y) * ldinv[ld];
        uint2 r; r.x = (unsigned)srcn; r.y = __float_as_uint(nv);
        csr[p] = r;
    }
}

// copy x (50000x128 fp32) into Th slice 0 (f16, row stride 384)
__global__ void k_copy_x(const float* __restrict__ x, __half* __restrict__ Th, int n2) {
    int i = blockIdx.x * blockDim.x + threadIdx.x;  // half2 index
    if (i < n2) {
        int node = i >> 6;
        int c2 = (i & 63) * 2;
        float2 v = *(const float2*)&x[(size_t)node * 128 + c2];
        *(__half2*)&Th[(size_t)node * 384 + c2] = __floats2half2_rn(v.x, v.y);
    }
}

// Build adjusted transposed weights (folds Chebyshev recombination):
// out = T0*(W0-W2) + T1*W1 + U*(2*W2), U = L*T1   [T2 = 2U - T0 never formed]
// W (384 x C fp32, k = kcheb*128 + cin) -> Wt (C x 384 f16)
__global__ void k_wt(const float* __restrict__ W, __half* __restrict__ Wt, int C) {
    int i = blockIdx.x * blockDim.x + threadIdx.x;
    if (i < C * 384) {
        int n = i / 384, k = i % 384;
        int kc = k >> 7, cin = k & 127;
        float v;
        if (kc == 0)      v = W[(size_t)k * C + n] - W[(size_t)(256 + cin) * C + n];
        else if (kc == 1) v = W[(size_t)k * C + n];
        else              v = 2.f * W[(size_t)k * C + n];
        Wt[i] = __float2half(v);
    }
}

// ---------- SpMM: one wave per node; 4 edges per gather instruction ----------
// Lane l loads f16x8 (16B, feats (l&15)*8..+8) of edge j+4k+(l>>4): one wave64
// gather covers 4 edges (R5 profile: bound by TA address throughput at 1
// gather instr/edge; this cuts gather instrs 4x). 8 gathers (32 edges) in
// flight per iter; partials reduced across edge-groups via shfl_xor at end.
__global__ __launch_bounds__(256) void k_spmm(__half* Th, const int* __restrict__ row_start,
                                              const uint2* __restrict__ csr,
                                              int in_off, int out_off) {
    int node = blockIdx.x * 4 + (threadIdx.x >> 6);
    int lane = threadIdx.x & 63;
    int eg = lane >> 4;        // edge-in-group 0..3
    int fs = lane & 15;        // feature slice: feats [fs*8, fs*8+8)
    int s = row_start[node];
    int e = row_start[node + 1];
    const __half* Tbase = Th + in_off + fs * 8;
    float acc[8];
    #pragma unroll
    for (int f = 0; f < 8; f++) acc[f] = 0.f;

    int j = s;
    for (; j + 32 <= e; j += 32) {
        uint2 mye = csr[j + (lane & 31)];
        int sp[8]; float nv[8];
        #pragma unroll
        for (int k = 0; k < 8; k++) {
            int li = 4 * k + eg;
            sp[k] = __shfl((int)mye.x, li);
            nv[k] = __uint_as_float(__shfl((int)mye.y, li));
        }
        f16x8 r[8];
        #pragma unroll
        for (int k = 0; k < 8; k++)
            r[k] = *(const f16x8*)&Tbase[(size_t)sp[k] * 384];
        #pragma unroll
        for (int k = 0; k < 8; k++)
            #pragma unroll
            for (int f = 0; f < 8; f++)
                acc[f] = fmaf(nv[k], (float)r[k][f], acc[f]);
    }
    int rem = e - j;
    if (rem > 0) {
        uint2 mye = csr[j + min(lane & 31, rem - 1)];
        int sp[8]; float nv[8];
        #pragma unroll
        for (int k = 0; k < 8; k++) {
            int li = 4 * k + eg;
            int sli = (li < rem) ? li : 0;
            sp[k] = __shfl((int)mye.x, sli);
            float nvv = __uint_as_float(__shfl((int)mye.y, sli));
            nv[k] = (li < rem) ? nvv : 0.f;
        }
        f16x8 r[8];
        #pragma unroll
        for (int k = 0; k < 8; k++)
            r[k] = *(const f16x8*)&Tbase[(size_t)sp[k] * 384];
        #pragma unroll
        for (int k = 0; k < 8; k++)
            #pragma unroll
            for (int f = 0; f < 8; f++)
                acc[f] = fmaf(nv[k], (float)r[k][f], acc[f]);
    }
    // reduce the 4 edge-group partials (lanes differing in bits 4..5)
    #pragma unroll
    for (int f = 0; f < 8; f++) {
        acc[f] += __shfl_xor(acc[f], 16);
        acc[f] += __shfl_xor(acc[f], 32);
    }
    if (eg == 0) {
        f16x8 o;
        #pragma unroll
        for (int f = 0; f < 8; f++) o[f] = (_Float16)acc[f];
        *(f16x8*)&Th[(size_t)node * 384 + out_off + fs * 8] = o;
    }
}

// ---------- MFMA GEMM: out = sigmoid(A[Mx384 f16] @ Wt^T[384xC f16] + b) ----------
// mfma_f32_16x16x32_f16: A[m=lane&15][k=(lane>>4)*8+j]; C/D col=lane&15,row=(lane>>4)*4+r.
// A and out may alias (rows owned exclusively per block) -> no __restrict__.
template <int C>
__global__ __launch_bounds__(256) void k_gemm(const __half* A, const __half* __restrict__ Wt,
                                              const float* __restrict__ bias, void* out,
                                              int mode, int M) {
    constexpr int NF = C / 16;
    __shared__ _Float16 As[64][56];
    __shared__ _Float16 Bs[C][56];
    int tid = threadIdx.x;
    int wave = tid >> 6, lane = tid & 63;
    int lm = lane & 15, lq = lane >> 4;
    int m0 = blockIdx.x * 64;
    f32x4 acc[NF];
    for (int nf = 0; nf < NF; nf++) acc[nf] = (f32x4)0.0f;

    for (int k0 = 0; k0 < 384; k0 += 32) {
        {
            int r = tid >> 2, q = tid & 3;
            int row = m0 + r;
            if (row >= M) row = M - 1;
            *(f16x8*)&As[r][q * 8] = *(const f16x8*)&A[(size_t)row * 384 + k0 + q * 8];
        }
        for (int i = 0; i < (C * 4) / 256; i++) {
            int idx = tid + i * 256;
            int n = idx >> 2, q = idx & 3;
            *(f16x8*)&Bs[n][q * 8] = *(const f16x8*)&Wt[(size_t)n * 384 + k0 + q * 8];
        }
        __syncthreads();
        f16x8 a = *(const f16x8*)&As[wave * 16 + lm][lq * 8];
        for (int nf = 0; nf < NF; nf++) {
            f16x8 b = *(const f16x8*)&Bs[nf * 16 + lm][lq * 8];
            acc[nf] = __builtin_amdgcn_mfma_f32_16x16x32_f16(a, b, acc[nf], 0, 0, 0);
        }
        __syncthreads();
    }
    for (int nf = 0; nf < NF; nf++) {
        for (int r = 0; r < 4; r++) {
            int grow = m0 + wave * 16 + lq * 4 + r;
            int col = nf * 16 + lm;
            if (grow < M) {
                float v = acc[nf][r] + bias[col];
                v = 1.f / (1.f + expf(-v));
                if (mode == 0)
                    ((__half*)out)[(size_t)grow * 384 + col] = __float2half(v);
                else
                    ((float*)out)[(size_t)grow * C + col] = v;
            }
        }
    }
}

extern "C" void kernel_launch(void* const* d_in, const int* in_sizes, int n_in,
                              void* d_out, int out_size, void* d_ws, size_t ws_size,
                              hipStream_t stream) {
    const float* x  = (const float*)d_in[0];
    const int*   ei = (const int*)d_in[1];
    const float* ew = (const float*)d_in[2];
    const float* W0 = (const float*)d_in[3];
    const float* b0 = (const float*)d_in[4];
    const float* W1 = (const float*)d_in[5];
    const float* b1 = (const float*)d_in[6];
    const float* W2 = (const float*)d_in[7];
    const float* b2 = (const float*)d_in[8];
    const int* src = ei;
    const int* dst = ei + N_EDGES;

    char* ws = (char*)d_ws;
    size_t off = 0;
    auto alloc = [&](size_t bytes) -> char* {
        size_t p = (off + 255) & ~(size_t)255;
        off = p + bytes;
        return ws + p;
    };
    __half* Th      = (__half*)alloc((size_t)N_NODES * 384 * 2);   // [T0|T1|U] f16
    uint2*  csr     = (uint2*)alloc((size_t)N_EDGES * 8);          // (src, norm)
    uint2*  dsw     = (uint2*)alloc((size_t)N_EDGES * 8);          // dst-sorted (src|dl, w)
    uint2*  ssw     = (uint2*)alloc((size_t)N_EDGES * 8);          // src-sorted (sl, w)
    int*    bcnt_d  = (int*)alloc((size_t)EBLK * 256 * 4);
    int*    bcnt_s  = (int*)alloc((size_t)EBLK * 256 * 4);
    int*    btot    = (int*)alloc(512 * 4);
    int*    bstart_d= (int*)alloc(257 * 4);
    int*    bstart_s= (int*)alloc(257 * 4);
    int*    row_start = (int*)alloc((size_t)(N_NODES + 1) * 4);
    float*  dinv    = (float*)alloc((size_t)N_NODES * 4);
    __half* Wt0     = (__half*)alloc((size_t)128 * 384 * 2);
    __half* Wt1     = (__half*)alloc((size_t)128 * 384 * 2);
    __half* Wt2     = (__half*)alloc((size_t)64 * 384 * 2);

    // dual bucket sort; zero device-scope atomics anywhere
    k_bcount<<<EBLK, 256, 0, stream>>>(src, dst, bcnt_d, bcnt_s);
    k_bscan1<<<512, 256, 0, stream>>>(bcnt_d, bcnt_s, btot);
    k_bscan2<<<1, 256, 0, stream>>>(btot, bstart_d, bstart_s, row_start);
    k_bscatter<<<EBLK, 256, 0, stream>>>(src, dst, ew, bcnt_d, bcnt_s,
                                         bstart_d, bstart_s, dsw, ssw);
    k_sdeg<<<NBUCK, 256, 0, stream>>>(ssw, bstart_s, dinv);
    k_bcsr<<<NBUCK, 256, 0, stream>>>(dsw, bstart_d, dinv, row_start, csr);

    k_copy_x<<<(N_NODES * 64 + 255) / 256, 256, 0, stream>>>(x, Th, N_NODES * 64);
    k_wt<<<(128 * 384 + 255) / 256, 256, 0, stream>>>(W0, Wt0, 128);
    k_wt<<<(128 * 384 + 255) / 256, 256, 0, stream>>>(W1, Wt1, 128);
    k_wt<<<(64 * 384 + 255) / 256, 256, 0, stream>>>(W2, Wt2, 64);

    const __half* Wl[3] = {Wt0, Wt1, Wt2};
    const float*  bl[3] = {b0, b1, b2};
    int gemm_blocks = (N_NODES + 63) / 64;
    for (int l = 0; l < 3; l++) {
        k_spmm<<<N_NODES / 4, 256, 0, stream>>>(Th, row_start, csr, 0, 128);    // T1 = L*T0
        k_spmm<<<N_NODES / 4, 256, 0, stream>>>(Th, row_start, csr, 128, 256);  // U  = L*T1
        if (l < 2)
            k_gemm<128><<<gemm_blocks, 256, 0, stream>>>(Th, Wl[l], bl[l], Th, 0, N_NODES);
        else
            k_gemm<64><<<gemm_blocks, 256, 0, stream>>>(Th, Wl[l], bl[l], d_out, 1, N_NODES);
    }
}

// Round 8
// 521.992 us; speedup vs baseline: 2.2371x; 1.0631x over previous
//
#include <hip/hip_runtime.h>
#include <hip/hip_fp16.h>
#include <math.h>

#define N_NODES 50000
#define N_EDGES 1600000
#define NBUCK 196          // node >> 8 buckets (50000/256)
#define EBLK 400           // edge blocks for sort
#define CHUNK 4000         // edges per block (EBLK*CHUNK == N_EDGES)

typedef _Float16 f16x8 __attribute__((ext_vector_type(8)));
typedef _Float16 f16x4 __attribute__((ext_vector_type(4)));
typedef float f32x4 __attribute__((ext_vector_type(4)));

union HBits { __half h; unsigned short u; };

// ---------- dual bucket sort (dst-keyed for CSR, src-keyed for deg) ----------
__global__ __launch_bounds__(256) void k_bcount(const int* __restrict__ src,
                                                const int* __restrict__ dst,
                                                int* __restrict__ bcnt_d,
                                                int* __restrict__ bcnt_s) {
    __shared__ int lcd[256];
    __shared__ int lcs[256];
    int tid = threadIdx.x;
    lcd[tid] = 0; lcs[tid] = 0;
    __syncthreads();
    int base = blockIdx.x * CHUNK;
    for (int i = tid; i < CHUNK; i += 256) {
        atomicAdd(&lcd[dst[base + i] >> 8], 1);
        atomicAdd(&lcs[src[base + i] >> 8], 1);
    }
    __syncthreads();
    bcnt_d[blockIdx.x * 256 + tid] = lcd[tid];
    bcnt_s[blockIdx.x * 256 + tid] = lcs[tid];
}

// per-bucket scan over edge-blocks (parallel)
__global__ __launch_bounds__(256) void k_bscan1(int* __restrict__ bcnt_d,
                                                int* __restrict__ bcnt_s,
                                                int* __restrict__ btot) {
    int b = blockIdx.x & 255;
    int* bcnt = (blockIdx.x >> 8) ? bcnt_s : bcnt_d;
    int tid = threadIdx.x;
    int k0 = 2 * tid;
    int v0 = (k0 < EBLK) ? bcnt[k0 * 256 + b] : 0;
    int v1 = (k0 + 1 < EBLK) ? bcnt[(k0 + 1) * 256 + b] : 0;
    int pair = v0 + v1;
    __shared__ int s[256];
    s[tid] = pair;
    __syncthreads();
    for (int off = 1; off < 256; off <<= 1) {
        int t = (tid >= off) ? s[tid - off] : 0;
        __syncthreads();
        s[tid] += t;
        __syncthreads();
    }
    int excl = s[tid] - pair;
    if (k0 < EBLK)     bcnt[k0 * 256 + b] = excl;
    if (k0 + 1 < EBLK) bcnt[(k0 + 1) * 256 + b] = excl + v0;
    if (tid == 255) btot[(blockIdx.x >> 8) * 256 + b] = s[255];
}

__global__ __launch_bounds__(256) void k_bscan2(const int* __restrict__ btot,
                                                int* __restrict__ bstart_d,
                                                int* __restrict__ bstart_s,
                                                int* __restrict__ row_start) {
    __shared__ int s[256];
    int b = threadIdx.x;
    int v = btot[b];
    s[b] = v;
    __syncthreads();
    for (int off = 1; off < 256; off <<= 1) {
        int t = (b >= off) ? s[b - off] : 0;
        __syncthreads();
        s[b] += t;
        __syncthreads();
    }
    bstart_d[b] = s[b] - v;
    if (b == 0) {
        bstart_d[256] = N_EDGES;
        row_start[N_NODES] = N_EDGES;
    }
    __syncthreads();
    int v2 = btot[256 + b];
    s[b] = v2;
    __syncthreads();
    for (int off = 1; off < 256; off <<= 1) {
        int t = (b >= off) ? s[b - off] : 0;
        __syncthreads();
        s[b] += t;
        __syncthreads();
    }
    bstart_s[b] = s[b] - v2;
    if (b == 0) bstart_s[256] = N_EDGES;
}

// scatter packed records into both sorted orders (LDS cursors only)
__global__ __launch_bounds__(256) void k_bscatter(const int* __restrict__ src,
                                                  const int* __restrict__ dst,
                                                  const float* __restrict__ w,
                                                  const int* __restrict__ bcnt_d,
                                                  const int* __restrict__ bcnt_s,
                                                  const int* __restrict__ bstart_d,
                                                  const int* __restrict__ bstart_s,
                                                  uint2* __restrict__ dsw,
                                                  uint2* __restrict__ ssw) {
    __shared__ int curd[256];
    __shared__ int curs[256];
    int tid = threadIdx.x;
    curd[tid] = bcnt_d[blockIdx.x * 256 + tid] + bstart_d[tid];
    curs[tid] = bcnt_s[blockIdx.x * 256 + tid] + bstart_s[tid];
    __syncthreads();
    int base = blockIdx.x * CHUNK;
    for (int i = tid; i < CHUNK; i += 256) {
        int d = dst[base + i];
        int ss = src[base + i];
        float wi = w[base + i];
        unsigned wb = __float_as_uint(wi);
        int p = atomicAdd(&curd[d >> 8], 1);   // LDS atomic
        uint2 r; r.x = (unsigned)ss | ((unsigned)(d & 255) << 16); r.y = wb;
        dsw[p] = r;
        int q = atomicAdd(&curs[ss >> 8], 1);  // LDS atomic
        uint2 r2; r2.x = (unsigned)(ss & 255); r2.y = wb;
        ssw[q] = r2;
    }
}

// deg per src-bucket -> dinv
__global__ __launch_bounds__(256) void k_sdeg(const uint2* __restrict__ ssw,
                                              const int* __restrict__ bstart_s,
                                              float* __restrict__ dinv) {
    __shared__ float h[256];
    int tid = threadIdx.x;
    int b = blockIdx.x;
    h[tid] = 0.f;
    __syncthreads();
    int e0 = bstart_s[b], e1 = bstart_s[b + 1];
    for (int i = e0 + tid; i < e1; i += 256) {
        uint2 r = ssw[i];
        atomicAdd(&h[r.x & 255], __uint_as_float(r.y));  // LDS atomic
    }
    __syncthreads();
    int node = (b << 8) + tid;
    if (node < N_NODES) {
        float d = h[tid];
        dinv[node] = d > 0.f ? rsqrtf(fmaxf(d, 1e-30f)) : 0.f;
    }
}

// per-bucket CSR build + inline norm; csr entry = src(16b) | f16norm << 16
__global__ __launch_bounds__(256) void k_bcsr(const uint2* __restrict__ dsw,
                                              const int* __restrict__ bstart_d,
                                              const float* __restrict__ dinv,
                                              int* __restrict__ row_start,
                                              unsigned* __restrict__ csr4) {
    __shared__ int ncnt[256];
    __shared__ int cur[256];
    __shared__ int sc[256];
    __shared__ float ldinv[256];
    int tid = threadIdx.x;
    int b = blockIdx.x;
    int node = (b << 8) + tid;
    ncnt[tid] = 0;
    ldinv[tid] = (node < N_NODES) ? dinv[node] : 0.f;
    __syncthreads();
    int e0 = bstart_d[b], e1 = bstart_d[b + 1];
    for (int i = e0 + tid; i < e1; i += 256)
        atomicAdd(&ncnt[(dsw[i].x >> 16) & 255], 1);  // LDS atomic
    __syncthreads();
    int v = ncnt[tid];
    sc[tid] = v;
    __syncthreads();
    for (int off = 1; off < 256; off <<= 1) {
        int t = (tid >= off) ? sc[tid - off] : 0;
        __syncthreads();
        sc[tid] += t;
        __syncthreads();
    }
    int excl = sc[tid] - v;
    cur[tid] = excl;
    if (node < N_NODES) row_start[node] = e0 + excl;
    __syncthreads();
    for (int i = e0 + tid; i < e1; i += 256) {
        uint2 sw = dsw[i];
        int srcn = sw.x & 0xFFFF;
        int ld = (sw.x >> 16) & 255;
        int p = e0 + atomicAdd(&cur[ld], 1);  // LDS atomic
        float nv = -dinv[srcn] * __uint_as_float(sw.y) * ldinv[ld];
        HBits hb; hb.h = __float2half(nv);
        csr4[p] = (unsigned)srcn | ((unsigned)hb.u << 16);
    }
}

// x fp32 -> X f16 (N x 128 contiguous)
__global__ void k_cvt_x(const float* __restrict__ x, __half* __restrict__ X, int n4) {
    int i = blockIdx.x * blockDim.x + threadIdx.x;
    if (i < n4) {
        float4 v = *(const float4*)&x[(size_t)i * 4];
        f16x4 o;
        o[0] = (_Float16)v.x; o[1] = (_Float16)v.y;
        o[2] = (_Float16)v.z; o[3] = (_Float16)v.w;
        *(f16x4*)&X[(size_t)i * 4] = o;
    }
}

// Build combined transposed weights for one layer:
// Wt[n*128 + k], n in [0,3C): slice0 = 2*W2, slice1 = W1, slice2 = W0 - W2.
// W layout (3,128,C): W[(kcheb*128 + cin)*C + cout]
__global__ void k_wt(const float* __restrict__ W, __half* __restrict__ Wt, int C) {
    int i = blockIdx.x * blockDim.x + threadIdx.x;
    if (i < 3 * C * 128) {
        int n = i >> 7, k = i & 127;
        int slice = n / C, c = n % C;
        float v;
        if (slice == 0)      v = 2.f * W[(size_t)(256 + k) * C + c];
        else if (slice == 1) v = W[(size_t)(128 + k) * C + c];
        else                 v = W[(size_t)k * C + c] - W[(size_t)(256 + k) * C + c];
        Wt[i] = __float2half(v);
    }
}

// ---------- SpMM: one wave per node, multi-edge-per-gather ----------
// out[node] = (SIG ? sigmoid(acc + Add[node] + bias) : acc + Add[node])
// acc = sum_e norm[e] * Xin[src[e]]   (FW features)
// FW=128: 4 edges/gather-instr (16 feat-lanes); FW=64: 8 edges/instr.
template <int FW, int SIG, int F32>
__global__ __launch_bounds__(256) void k_spmm(const __half* __restrict__ Xin, int st_in,
                                              const __half* __restrict__ Add, int st_add,
                                              void* __restrict__ outp, int st_out,
                                              const float* __restrict__ bias,
                                              const int* __restrict__ row_start,
                                              const unsigned* __restrict__ csr4) {
    constexpr int NL = FW / 8;      // feature lanes per edge (16 or 8)
    constexpr int EG = 64 / NL;     // edges per gather instr (4 or 8)
    constexpr int KE = 32 / EG;     // edges per lane per iter (8 or 4)
    int node = blockIdx.x * 4 + (threadIdx.x >> 6);
    int lane = threadIdx.x & 63;
    int eg = lane / NL;
    int fs = lane % NL;
    int s = row_start[node];
    int e = row_start[node + 1];
    const __half* Tbase = Xin + fs * 8;
    float acc[8];
    #pragma unroll
    for (int f = 0; f < 8; f++) acc[f] = 0.f;

    int j = s;
    for (; j + 32 <= e; j += 32) {
        unsigned mye = csr4[j + (lane & 31)];
        int sp[KE]; float nv[KE];
        #pragma unroll
        for (int k = 0; k < KE; k++) {
            unsigned ent = (unsigned)__shfl((int)mye, EG * k + eg);
            sp[k] = (int)(ent & 0xFFFFu);
            HBits hb; hb.u = (unsigned short)(ent >> 16);
            nv[k] = __half2float(hb.h);
        }
        f16x8 r[KE];
        #pragma unroll
        for (int k = 0; k < KE; k++)
            r[k] = *(const f16x8*)&Tbase[(size_t)sp[k] * st_in];
        #pragma unroll
        for (int k = 0; k < KE; k++)
            #pragma unroll
            for (int f = 0; f < 8; f++)
                acc[f] = fmaf(nv[k], (float)r[k][f], acc[f]);
    }
    int rem = e - j;
    if (rem > 0) {
        unsigned mye = csr4[j + min(lane & 31, rem - 1)];
        int sp[KE]; float nv[KE];
        #pragma unroll
        for (int k = 0; k < KE; k++) {
            int li = EG * k + eg;
            int sli = (li < rem) ? li : 0;
            unsigned ent = (unsigned)__shfl((int)mye, sli);
            sp[k] = (int)(ent & 0xFFFFu);
            HBits hb; hb.u = (unsigned short)(ent >> 16);
            float nvv = __half2float(hb.h);
            nv[k] = (li < rem) ? nvv : 0.f;
        }
        f16x8 r[KE];
        #pragma unroll
        for (int k = 0; k < KE; k++)
            r[k] = *(const f16x8*)&Tbase[(size_t)sp[k] * st_in];
        #pragma unroll
        for (int k = 0; k < KE; k++)
            #pragma unroll
            for (int f = 0; f < 8; f++)
                acc[f] = fmaf(nv[k], (float)r[k][f], acc[f]);
    }
    // reduce edge-group partials
    #pragma unroll
    for (int f = 0; f < 8; f++)
        for (int m = NL; m < 64; m <<= 1)
            acc[f] += __shfl_xor(acc[f], m);
    if (eg == 0) {
        f16x8 av = *(const f16x8*)&Add[(size_t)node * st_add + fs * 8];
        float v[8];
        #pragma unroll
        for (int f = 0; f < 8; f++) v[f] = acc[f] + (float)av[f];
        if (SIG) {
            #pragma unroll
            for (int f = 0; f < 8; f++) {
                v[f] += bias[fs * 8 + f];
                v[f] = 1.f / (1.f + expf(-v[f]));
            }
        }
        if (F32) {
            float* o = (float*)outp + (size_t)node * st_out + fs * 8;
            #pragma unroll
            for (int f = 0; f < 8; f++) o[f] = v[f];
        } else {
            f16x8 o;
            #pragma unroll
            for (int f = 0; f < 8; f++) o[f] = (_Float16)v[f];
            *(f16x8*)((__half*)outp + (size_t)node * st_out + fs * 8) = o;
        }
    }
}

// ---------- MFMA GEMM: G[M x 3C] = X[M x 128] @ Wt^T, col-chunk CC per block.y
// mfma_f32_16x16x32_f16: A[m=lane&15][k=(lane>>4)*8+j]; C/D col=lane&15,row=(lane>>4)*4+r.
template <int CC>
__global__ __launch_bounds__(256) void k_gemm(const __half* __restrict__ A,
                                              const __half* __restrict__ Wt,
                                              __half* __restrict__ G, int M) {
    constexpr int NF = CC / 16;
    constexpr int N3 = 3 * CC;
    __shared__ _Float16 As[64][56];
    __shared__ _Float16 Bs[CC][56];
    int tid = threadIdx.x;
    int wave = tid >> 6, lane = tid & 63;
    int lm = lane & 15, lq = lane >> 4;
    int m0 = blockIdx.x * 64;
    int n0 = blockIdx.y * CC;
    f32x4 acc[NF];
    for (int nf = 0; nf < NF; nf++) acc[nf] = (f32x4)0.0f;

    for (int k0 = 0; k0 < 128; k0 += 32) {
        {
            int r = tid >> 2, q = tid & 3;
            int row = m0 + r;
            if (row >= M) row = M - 1;
            *(f16x8*)&As[r][q * 8] = *(const f16x8*)&A[(size_t)row * 128 + k0 + q * 8];
        }
        for (int i = 0; i < CC / 64; i++) {
            int idx = tid + i * 256;
            int n = idx >> 2, q = idx & 3;
            *(f16x8*)&Bs[n][q * 8] = *(const f16x8*)&Wt[(size_t)(n0 + n) * 128 + k0 + q * 8];
        }
        __syncthreads();
        f16x8 a = *(const f16x8*)&As[wave * 16 + lm][lq * 8];
        for (int nf = 0; nf < NF; nf++) {
            f16x8 b = *(const f16x8*)&Bs[nf * 16 + lm][lq * 8];
            acc[nf] = __builtin_amdgcn_mfma_f32_16x16x32_f16(a, b, acc[nf], 0, 0, 0);
        }
        __syncthreads();
    }
    for (int nf = 0; nf < NF; nf++) {
        for (int r = 0; r < 4; r++) {
            int grow = m0 + wave * 16 + lq * 4 + r;
            int col = n0 + nf * 16 + lm;
            if (grow < M)
                G[(size_t)grow * N3 + col] = __float2half(acc[nf][r]);
        }
    }
}

extern "C" void kernel_launch(void* const* d_in, const int* in_sizes, int n_in,
                              void* d_out, int out_size, void* d_ws, size_t ws_size,
                              hipStream_t stream) {
    const float* x  = (const float*)d_in[0];
    const int*   ei = (const int*)d_in[1];
    const float* ew = (const float*)d_in[2];
    const float* W0 = (const float*)d_in[3];
    const float* b0 = (const float*)d_in[4];
    const float* W1 = (const float*)d_in[5];
    const float* b1 = (const float*)d_in[6];
    const float* W2 = (const float*)d_in[7];
    const float* b2 = (const float*)d_in[8];
    const int* src = ei;
    const int* dst = ei + N_EDGES;

    char* ws = (char*)d_ws;
    size_t off = 0;
    auto alloc = [&](size_t bytes) -> char* {
        size_t p = (off + 255) & ~(size_t)255;
        off = p + bytes;
        return ws + p;
    };
    __half*   X      = (__half*)alloc((size_t)N_NODES * 128 * 2);   // activations (in-place per layer)
    __half*   G      = (__half*)alloc((size_t)N_NODES * 384 * 2);   // [P|Q|S] per layer
    __half*   TMP    = (__half*)alloc((size_t)N_NODES * 128 * 2);   // L*P intermediate
    unsigned* csr4   = (unsigned*)alloc((size_t)N_EDGES * 4);       // src | f16norm<<16
    uint2*    dsw    = (uint2*)alloc((size_t)N_EDGES * 8);
    uint2*    ssw    = (uint2*)alloc((size_t)N_EDGES * 8);
    int*      bcnt_d = (int*)alloc((size_t)EBLK * 256 * 4);
    int*      bcnt_s = (int*)alloc((size_t)EBLK * 256 * 4);
    int*      btot   = (int*)alloc(512 * 4);
    int*      bstart_d = (int*)alloc(257 * 4);
    int*      bstart_s = (int*)alloc(257 * 4);
    int*      row_start= (int*)alloc((size_t)(N_NODES + 1) * 4);
    float*    dinv   = (float*)alloc((size_t)N_NODES * 4);
    __half*   Wt0    = (__half*)alloc((size_t)384 * 128 * 2);
    __half*   Wt1    = (__half*)alloc((size_t)384 * 128 * 2);
    __half*   Wt2    = (__half*)alloc((size_t)192 * 128 * 2);

    // dual bucket sort; zero device-scope atomics anywhere
    k_bcount<<<EBLK, 256, 0, stream>>>(src, dst, bcnt_d, bcnt_s);
    k_bscan1<<<512, 256, 0, stream>>>(bcnt_d, bcnt_s, btot);
    k_bscan2<<<1, 256, 0, stream>>>(btot, bstart_d, bstart_s, row_start);
    k_bscatter<<<EBLK, 256, 0, stream>>>(src, dst, ew, bcnt_d, bcnt_s,
                                         bstart_d, bstart_s, dsw, ssw);
    k_sdeg<<<NBUCK, 256, 0, stream>>>(ssw, bstart_s, dinv);
    k_bcsr<<<NBUCK, 256, 0, stream>>>(dsw, bstart_d, dinv, row_start, csr4);

    k_cvt_x<<<(N_NODES * 32 + 255) / 256, 256, 0, stream>>>(x, X, N_NODES * 32);
    k_wt<<<(3 * 128 * 128 + 255) / 256, 256, 0, stream>>>(W0, Wt0, 128);
    k_wt<<<(3 * 128 * 128 + 255) / 256, 256, 0, stream>>>(W1, Wt1, 128);
    k_wt<<<(3 * 64 * 128 + 255) / 256, 256, 0, stream>>>(W2, Wt2, 64);

    int gb = (N_NODES + 63) / 64;  // 782
    // layer 0: G = X @ [Wc|Wb|Wa];  TMP = L*P + Q;  X = sigmoid(L*TMP + S + b0)
    k_gemm<128><<<dim3(gb, 3), 256, 0, stream>>>(X, Wt0, G, N_NODES);
    k_spmm<128, 0, 0><<<N_NODES / 4, 256, 0, stream>>>(G, 384, G + 128, 384, TMP, 128,
                                                       nullptr, row_start, csr4);
    k_spmm<128, 1, 0><<<N_NODES / 4, 256, 0, stream>>>(TMP, 128, G + 256, 384, X, 128,
                                                       b0, row_start, csr4);
    // layer 1
    k_gemm<128><<<dim3(gb, 3), 256, 0, stream>>>(X, Wt1, G, N_NODES);
    k_spmm<128, 0, 0><<<N_NODES / 4, 256, 0, stream>>>(G, 384, G + 128, 384, TMP, 128,
                                                       nullptr, row_start, csr4);
    k_spmm<128, 1, 0><<<N_NODES / 4, 256, 0, stream>>>(TMP, 128, G + 256, 384, X, 128,
                                                       b1, row_start, csr4);
    // layer 2 (C=64): G = N x 192
    k_gemm<64><<<dim3(gb, 3), 256, 0, stream>>>(X, Wt2, G, N_NODES);
    k_spmm<64, 0, 0><<<N_NODES / 4, 256, 0, stream>>>(G, 192, G + 64, 192, TMP, 64,
                                                      nullptr, row_start, csr4);
    k_spmm<64, 1, 1><<<N_NODES / 4, 256, 0, stream>>>(TMP, 64, G + 128, 192, d_out, 64,
                                                      b2, row_start, csr4);
}